// Round 3
// baseline (185.846 us; speedup 1.0000x reference)
//
#include <hip/hip_runtime.h>

// Conv2D 15x15 valid, 4096^2 fp32 -> 4082^2 fp32, bf16-MFMA Toeplitz band.
// Round 3: y-marching blocks + double-buffered LDS staging to kill the
// stage->barrier->compute serialization that left all pipes <25% busy.
//
// Block (256 thr, 4 waves) owns a 64-col x 256-row strip, marched in 4 steps
// of 64x64 outputs. Per step: issue global prefetch (regs) for step s+1,
// MFMA-compute step s from buf[s&1], store, cvt+ds_write prefetch into
// buf[(s+1)&1], one barrier. B-fragments (15 x bf16x8) live in registers for
// the whole block; their LDS build table is overlaid on the x double-buffer
// (freed after init). LDS = 2 x 13.7 KB = 27.5 KB.

#define HIN 4096
#define WIN 4096
#define KH 15
#define KW 15
#define OH (HIN - KH + 1)  // 4082
#define OW (WIN - KW + 1)  // 4082

#define BX 64
#define BYSTEP 64
#define SSTEPS 4
#define XROWS (BYSTEP + KH - 1)     // 78
#define XCOLS 80                    // 64 + 14 pad to float4 multiple
#define LDSW 88                     // row stride (176 B -> 12-dword bank skew)
#define BUFSH (XROWS * LDSW)        // 6864 shorts per buffer
#define NSLOT (XROWS * (XCOLS / 4))  // 1560 float4 staging slots
#define NPF 7                        // ceil(1560/256)

typedef short bf16x8 __attribute__((ext_vector_type(8)));
typedef float f32x4  __attribute__((ext_vector_type(4)));

static __device__ inline short f2bf(float f) {  // fp32 -> bf16 RNE
    unsigned u = __float_as_uint(f);
    u += 0x7fffu + ((u >> 16) & 1u);
    return (short)(u >> 16);
}

static __device__ inline float4 load_clamped(const float* __restrict__ x,
                                             int gy, int gx) {
    if (gy > HIN - 1) gy = HIN - 1;
    if (gx + 3 <= WIN - 1) {
        return *reinterpret_cast<const float4*>(&x[(size_t)gy * WIN + gx]);
    }
    const float* row = &x[(size_t)gy * WIN];
    const int x0 = (gx + 0 > WIN - 1) ? WIN - 1 : gx + 0;
    const int x1 = (gx + 1 > WIN - 1) ? WIN - 1 : gx + 1;
    const int x2 = (gx + 2 > WIN - 1) ? WIN - 1 : gx + 2;
    const int x3 = (gx + 3 > WIN - 1) ? WIN - 1 : gx + 3;
    return make_float4(row[x0], row[x1], row[x2], row[x3]);
}

__global__ __launch_bounds__(256, 4)
void conv2d_mfma_march(const float* __restrict__ x,
                       const float* __restrict__ w,
                       const float* __restrict__ bias,
                       float* __restrict__ out) {
    __shared__ short lds[2 * BUFSH];   // 27456 B; B-table overlaid at init

    const int tid  = threadIdx.x;
    const int lane = tid & 63;
    const int wv   = tid >> 6;
    const int m    = lane & 15;
    const int q    = lane >> 4;
    const int ox0  = blockIdx.x * BX;
    const int ybase = blockIdx.y * (SSTEPS * BYSTEP);

    // ---- build B table (overlaid on x buffers), read to regs, then free ----
    // B-frag layout (16x16x32 B operand): lane L holds B[k=(L>>4)*8+j][n=L&15],
    // B[k][n] = w[kh][k-n] for 0 <= k-n < 15 else 0.
    for (int e = tid; e < 15 * 64; e += 256) {
        const int kh = e >> 6;
        const int L  = e & 63;
        const int n  = L & 15;
        const int qq = L >> 4;
        bf16x8 bv;
#pragma unroll
        for (int j = 0; j < 8; ++j) {
            const int d = qq * 8 + j - n;
            bv[j] = (d >= 0 && d < KW) ? f2bf(w[kh * KW + d]) : (short)0;
        }
        *reinterpret_cast<bf16x8*>(&lds[e * 8]) = bv;
    }
    __syncthreads();
    bf16x8 B[KH];
#pragma unroll
    for (int kh = 0; kh < KH; ++kh)
        B[kh] = *reinterpret_cast<const bf16x8*>(&lds[(kh * 64 + lane) * 8]);
    __syncthreads();   // B in regs; buffers may now be overwritten

    // ---- stage step 0 into buf0 ----
    for (int f = tid; f < NSLOT; f += 256) {
        const int r  = f / (XCOLS / 4);
        const int c4 = (f - r * (XCOLS / 4)) * 4;
        const float4 v = load_clamped(x, ybase + r, ox0 + c4);
        short4 s;
        s.x = f2bf(v.x); s.y = f2bf(v.y); s.z = f2bf(v.z); s.w = f2bf(v.w);
        *reinterpret_cast<short4*>(&lds[r * LDSW + c4]) = s;
    }
    __syncthreads();

    const float b0 = bias[0];

    for (int s = 0; s < SSTEPS; ++s) {
        const short* cur = &lds[(s & 1) * BUFSH];
        short*       nxt = &lds[((s + 1) & 1) * BUFSH];
        const int    oy0 = ybase + s * BYSTEP;
        const bool   has_next = (s + 1 < SSTEPS);

        // -- issue global prefetch for step s+1 (latency hidden by MFMA loop) --
        float4 pf[NPF];
        if (has_next) {
#pragma unroll
            for (int i = 0; i < NPF; ++i) {
                const int f = tid + i * 256;
                if (f < NSLOT) {
                    const int r  = f / (XCOLS / 4);
                    const int c4 = (f - r * (XCOLS / 4)) * 4;
                    pf[i] = load_clamped(x, oy0 + BYSTEP + r, ox0 + c4);
                }
            }
        }

        // -- compute 64x64 from cur: 15 kh x 4 t-tiles of 16x16x32 MFMA --
        f32x4 acc[4];
#pragma unroll
        for (int t = 0; t < 4; ++t) acc[t] = (f32x4){0.f, 0.f, 0.f, 0.f};

        const short* abase = cur + (wv * 16 + m) * LDSW + q * 8;
#pragma unroll
        for (int kh = 0; kh < KH; ++kh) {
#pragma unroll
            for (int t = 0; t < 4; ++t) {
                const bf16x8 a =
                    *reinterpret_cast<const bf16x8*>(abase + kh * LDSW + t * 16);
                acc[t] = __builtin_amdgcn_mfma_f32_16x16x32_bf16(a, B[kh], acc[t], 0, 0, 0);
            }
        }

        // -- epilogue: D layout col=lane&15, row=(lane>>4)*4+reg --
        const int row0 = oy0 + wv * 16 + q * 4;
#pragma unroll
        for (int t = 0; t < 4; ++t) {
            const int col = ox0 + t * 16 + m;
            if (col < OW) {
#pragma unroll
                for (int r = 0; r < 4; ++r) {
                    const int row = row0 + r;
                    if (row < OH)
                        out[(size_t)row * OW + col] = acc[t][r] + b0;
                }
            }
        }

        // -- cvt + LDS-write prefetch into back buffer --
        if (has_next) {
#pragma unroll
            for (int i = 0; i < NPF; ++i) {
                const int f = tid + i * 256;
                if (f < NSLOT) {
                    const int r  = f / (XCOLS / 4);
                    const int c4 = (f - r * (XCOLS / 4)) * 4;
                    short4 sv;
                    sv.x = f2bf(pf[i].x); sv.y = f2bf(pf[i].y);
                    sv.z = f2bf(pf[i].z); sv.w = f2bf(pf[i].w);
                    *reinterpret_cast<short4*>(&nxt[r * LDSW + c4]) = sv;
                }
            }
        }
        __syncthreads();
    }
}

extern "C" void kernel_launch(void* const* d_in, const int* in_sizes, int n_in,
                              void* d_out, int out_size, void* d_ws, size_t ws_size,
                              hipStream_t stream) {
    const float* x    = (const float*)d_in[0];
    const float* w    = (const float*)d_in[1];
    const float* bias = (const float*)d_in[2];
    float* out        = (float*)d_out;

    dim3 grid((OW + BX - 1) / BX, (OH + SSTEPS * BYSTEP - 1) / (SSTEPS * BYSTEP));  // 64 x 16
    dim3 block(256);
    conv2d_mfma_march<<<grid, block, 0, stream>>>(x, w, bias, out);
}

// Round 4
// 161.124 us; speedup vs baseline: 1.1534x; 1.1534x over previous
//
#include <hip/hip_runtime.h>

// Conv2D 15x15 valid, 4096^2 fp32 -> 4082^2 fp32, bf16-MFMA Toeplitz band.
// Round 4: back to round-2's single-barrier shape (cross-block overlap does
// the pipelining), but 128x128 tiles to amortize barrier/latency 4x, and
// B-fragments built per-lane from global w (no LDS B table, no extra
// barriers). LDS = 142 rows x 152-short stride = 43.2 KB -> 3 blocks/CU.
//
// Per wave: rows [32*wv, +32), 2 row-tiles x 8 col-tiles x 15 kh = 240
// v_mfma_f32_16x16x32_bf16, each fed by one ds_read_b128 (A frag) off a
// single base VGPR + immediate offset. Row stride 304 B = 76 dwords -> bank
// skew 12, only m<->m+8 alias (2-way = free). B: 15 x bf16x8 = 60 VGPRs.

#define HIN 4096
#define WIN 4096
#define KH 15
#define KW 15
#define OH (HIN - KH + 1)  // 4082
#define OW (WIN - KW + 1)  // 4082

#define BX 128
#define BY 128
#define XROWS (BY + KH - 1)       // 142 staged input rows
#define XCOLS 144                 // 128 + 14, padded to float4 multiple
#define LDSW 152                  // bf16 row stride (304 B, 16B-aligned)
#define NSLOT (XROWS * (XCOLS / 4))  // 5112 float4 staging slots

typedef short bf16x8 __attribute__((ext_vector_type(8)));
typedef float f32x4  __attribute__((ext_vector_type(4)));

static __device__ inline short f2bf(float f) {  // fp32 -> bf16 RNE
    unsigned u = __float_as_uint(f);
    u += 0x7fffu + ((u >> 16) & 1u);
    return (short)(u >> 16);
}

__global__ __launch_bounds__(256)
void conv2d_mfma_big(const float* __restrict__ x,
                     const float* __restrict__ w,
                     const float* __restrict__ bias,
                     float* __restrict__ out) {
    __shared__ short lds[XROWS * LDSW];   // 43168 B

    const int tid  = threadIdx.x;
    const int lane = tid & 63;
    const int wv   = tid >> 6;
    const int m    = lane & 15;
    const int q    = lane >> 4;
    const int ox0  = blockIdx.x * BX;
    const int oy0  = blockIdx.y * BY;

    // ---------------- stage x tile: 142 x 144 fp32 -> bf16 LDS ----------------
    for (int i = 0; i < (NSLOT + 255) / 256; ++i) {
        const int f = tid + i * 256;
        if (f < NSLOT) {
            const int r  = f / (XCOLS / 4);
            const int c4 = (f - r * (XCOLS / 4)) * 4;
            int gy = oy0 + r;
            if (gy > HIN - 1) gy = HIN - 1;   // clamped rows feed only masked outputs
            const int gx = ox0 + c4;
            float4 v;
            if (gx + 3 <= WIN - 1) {
                v = *reinterpret_cast<const float4*>(&x[(size_t)gy * WIN + gx]);
            } else {
                const float* row = &x[(size_t)gy * WIN];
                const int x0 = (gx + 0 > WIN - 1) ? WIN - 1 : gx + 0;
                const int x1 = (gx + 1 > WIN - 1) ? WIN - 1 : gx + 1;
                const int x2 = (gx + 2 > WIN - 1) ? WIN - 1 : gx + 2;
                const int x3 = (gx + 3 > WIN - 1) ? WIN - 1 : gx + 3;
                v = make_float4(row[x0], row[x1], row[x2], row[x3]);
            }
            short4 s;
            s.x = f2bf(v.x); s.y = f2bf(v.y); s.z = f2bf(v.z); s.w = f2bf(v.w);
            *reinterpret_cast<short4*>(&lds[r * LDSW + c4]) = s;
        }
    }

    // ---- B fragments, per-lane from global w (L1-resident 900 B), no LDS ----
    // B-frag layout (16x16x32 B-op): lane holds B[k=q*8+j][n=m], j=0..7,
    // B[k][n] = w[kh][k-n] for 0 <= k-n < 15 else 0.
    bf16x8 B[KH];
#pragma unroll
    for (int kh = 0; kh < KH; ++kh) {
#pragma unroll
        for (int j = 0; j < 8; ++j) {
            const int d = q * 8 + j - m;          // k - n
            B[kh][j] = (d >= 0 && d < KW) ? f2bf(w[kh * KW + d]) : (short)0;
        }
    }

    __syncthreads();   // the only barrier

    // ---------- compute: 2 row-tiles x 8 col-tiles x 15 kh MFMAs ----------
    f32x4 acc[2][8];
#pragma unroll
    for (int rv = 0; rv < 2; ++rv)
#pragma unroll
        for (int t = 0; t < 8; ++t) acc[rv][t] = (f32x4){0.f, 0.f, 0.f, 0.f};

    // A-frag lane addr: row (32*wv + 16*rv + m + kh), cols q*8 + t*16
    const short* abase = &lds[(wv * 32 + m) * LDSW + q * 8];
#pragma unroll
    for (int kh = 0; kh < KH; ++kh) {
#pragma unroll
        for (int rv = 0; rv < 2; ++rv) {
#pragma unroll
            for (int t = 0; t < 8; ++t) {
                const bf16x8 a = *reinterpret_cast<const bf16x8*>(
                    abase + (kh + rv * 16) * LDSW + t * 16);      // ds_read_b128
                acc[rv][t] =
                    __builtin_amdgcn_mfma_f32_16x16x32_bf16(a, B[kh], acc[rv][t], 0, 0, 0);
            }
        }
    }

    // ------------- epilogue: D layout col=lane&15, row=(lane>>4)*4+reg -------------
    const float b0 = bias[0];
#pragma unroll
    for (int rv = 0; rv < 2; ++rv) {
        const int row0 = oy0 + wv * 32 + rv * 16 + q * 4;
#pragma unroll
        for (int t = 0; t < 8; ++t) {
            const int col = ox0 + t * 16 + m;
            if (col < OW) {
#pragma unroll
                for (int r = 0; r < 4; ++r) {
                    const int row = row0 + r;
                    if (row < OH)
                        out[(size_t)row * OW + col] = acc[rv][t][r] + b0;
                }
            }
        }
    }
}

extern "C" void kernel_launch(void* const* d_in, const int* in_sizes, int n_in,
                              void* d_out, int out_size, void* d_ws, size_t ws_size,
                              hipStream_t stream) {
    const float* x    = (const float*)d_in[0];
    const float* w    = (const float*)d_in[1];
    const float* bias = (const float*)d_in[2];
    float* out        = (float*)d_out;

    dim3 grid((OW + BX - 1) / BX, (OH + BY - 1) / BY);  // 32 x 32
    dim3 block(256);
    conv2d_mfma_big<<<grid, block, 0, stream>>>(x, w, bias, out);
}